// Round 6
// baseline (118.570 us; speedup 1.0000x reference)
//
#include <hip/hip_runtime.h>

// RoundRobinGate: output = (0.0 scalar, one-hot [2,4096,16,512] f32, same tensor as
// bool->f32). Fully input-independent: 537 MB of zeros + 16,384 ones. Pure store-BW.
//
// Fill-shaped single kernel (mimics rocclr fillBufferAligned's proven 6.6-6.85 TB/s):
// 2048 blocks x 256 threads, 64 grid-stride iterations, one lane-contiguous float4
// nontemporal store per iteration (1 KB per wave-instruction, 8 MB iteration stride).
//
// Flat layout (float32), NTOT = 1 + 2*N1 = 134217729:
//   p = 0 -> scalar 0.0; p in [1,1+N1) -> one-hot (j=p-1); p in [1+N1,1+2N1) -> same.
// Span r (= p>>13, 16384 spans of 8192 floats): element 8192r is the previous row's
// offset-8191 element (never hot: hot <= 7935) or the p=0 scalar; row r's hot sits at
// span offset hl = hot+1 with i = r & 4095, hot = ((i&15)<<9)|(i>>4).
// Tail float p = 134217728 is never hot -> 0.0 (written by thread 0).
//
// Grid stride = 524288 quads = 256 spans exactly -> within-span quad position
// ql = t & 2047 is loop-invariant; per-iteration work is ~8 VALU + rare branch.

typedef float floatx4 __attribute__((ext_vector_type(4)));

#define NQ     33554432u        // float4 quads covering [0, 134217728) floats
#define NTHR   (2048u * 256u)   // grid threads; NQ / NTHR = 64 iterations

__global__ void __launch_bounds__(256) rr_gate_fill(floatx4* __restrict__ out4,
                                                    float* __restrict__ out) {
    const unsigned t  = blockIdx.x * 256u + threadIdx.x;
    const unsigned ql = t & 2047u;          // quad position within span (loop-invariant)
    unsigned r        = t >> 11;            // span id for iteration 0 (advances by 256)
    floatx4* p        = out4 + t;

#pragma unroll 8
    for (unsigned it = 0; it < 64u; ++it) {
        const unsigned i  = r & 4095u;                          // token row
        const unsigned hl = (((i & 15u) << 9) | (i >> 4)) + 1u; // hot offset in span
        floatx4 v = (floatx4)(0.0f);
        if (ql == (hl >> 2)) {              // rare: execz-skipped in ~31/32 waves
            const unsigned comp = hl & 3u;
            v.x = (comp == 0u) ? 1.0f : 0.0f;
            v.y = (comp == 1u) ? 1.0f : 0.0f;
            v.z = (comp == 2u) ? 1.0f : 0.0f;
            v.w = (comp == 3u) ? 1.0f : 0.0f;
        }
        __builtin_nontemporal_store(v, p);
        p += NTHR;
        r += 256u;
    }
    // Final odd element (index 134217728): always 0.
    if (t == 0) {
        out[134217728u] = 0.0f;
    }
}

extern "C" void kernel_launch(void* const* d_in, const int* in_sizes, int n_in,
                              void* d_out, int out_size, void* d_ws, size_t ws_size,
                              hipStream_t stream) {
    (void)d_in; (void)in_sizes; (void)n_in; (void)d_ws; (void)ws_size; (void)out_size;
    hipLaunchKernelGGL(rr_gate_fill, dim3(2048), dim3(256), 0, stream,
                       (floatx4*)d_out, (float*)d_out);
}